// Round 1
// baseline (934.386 us; speedup 1.0000x reference)
//
#include <hip/hip_runtime.h>

typedef __attribute__((ext_vector_type(4))) float f32x4;
typedef __attribute__((ext_vector_type(8))) short bf16x8;
typedef __attribute__((ext_vector_type(8))) unsigned short ushort8;
typedef unsigned short u16;
typedef unsigned int u32;

#define LDS_AS(p) ((__attribute__((address_space(3))) void*)(p))
#define GLB_AS(p) ((const __attribute__((address_space(1))) void*)(p))

__device__ __forceinline__ u16 f2b(float f) {
    u32 u = __builtin_bit_cast(u32, f);
    u32 r = (u + 0x7fffu + ((u >> 16) & 1u)) >> 16;
    return (u16)r;
}

// ---------------------------------------------------------------------------
// Weight prep: fp32 [K,N] -> bf16 [N,K] (transposed) for all 8 weights
// ---------------------------------------------------------------------------
struct PrepAll {
    const float* src[8];
    u16* dst[8];
    int K[8];
    int N[8];
};

__global__ __launch_bounds__(256) void prep_w(PrepAll p) {
    const int wi = blockIdx.y;
    const int K = p.K[wi], N = p.N[wi];
    const int e = blockIdx.x * 256 + threadIdx.x;
    if (e >= K * N) return;
    const int k = e / N, n = e % N;
    p.dst[wi][n * K + k] = f2b(p.src[wi][e]);
}

// Bm[s*8+h][i][j] = table_s[rel_idx(i,j)*8 + h], window 8x8
__global__ __launch_bounds__(64) void prep_bias(const float* __restrict__ t1,
                                                const float* __restrict__ t2,
                                                float* __restrict__ Bm) {
    const int j = threadIdx.x;   // 64
    const int i = blockIdx.x;    // 64
    const int hh = blockIdx.y;   // 16 = s*8+h
    const int s = hh >> 3, h = hh & 7;
    const int idx = ((i >> 3) - (j >> 3) + 7) * 15 + ((i & 7) - (j & 7) + 7);
    const float* tab = s ? t2 : t1;
    Bm[(long)hh * 4096 + i * 64 + j] = tab[idx * 8 + h];
}

// fp32 -> bf16 cast, 8 elems/thread
__global__ __launch_bounds__(256) void cast_bf(const float* __restrict__ in,
                                               u16* __restrict__ out) {
    const long i = (long)blockIdx.x * 256 + threadIdx.x;
    const float4 a = *(const float4*)(in + i * 8);
    const float4 b = *(const float4*)(in + i * 8 + 4);
    ushort8 o;
    o[0] = f2b(a.x); o[1] = f2b(a.y); o[2] = f2b(a.z); o[3] = f2b(a.w);
    o[4] = f2b(b.x); o[5] = f2b(b.y); o[6] = f2b(b.z); o[7] = f2b(b.w);
    *(ushort8*)(out + i * 8) = o;
}

// ---------------------------------------------------------------------------
// LayerNorm over C=256, one wave per row, fp32 in -> bf16 out
// ---------------------------------------------------------------------------
__global__ __launch_bounds__(256) void ln256(const float* __restrict__ x,
                                             const float* __restrict__ g,
                                             const float* __restrict__ b,
                                             u16* __restrict__ out) {
    const int lane = threadIdx.x & 63;
    const long row = (long)blockIdx.x * 4 + (threadIdx.x >> 6);
    const float4 v = *(const float4*)(x + row * 256 + lane * 4);
    float s = v.x + v.y + v.z + v.w;
    float s2 = v.x * v.x + v.y * v.y + v.z * v.z + v.w * v.w;
#pragma unroll
    for (int off = 32; off > 0; off >>= 1) {
        s += __shfl_xor(s, off);
        s2 += __shfl_xor(s2, off);
    }
    const float mu = s * (1.f / 256.f);
    const float var = s2 * (1.f / 256.f) - mu * mu;
    const float rr = rsqrtf(var + 1e-5f);
    const int c = lane * 4;
    const float4 gv = *(const float4*)(g + c);
    const float4 bv = *(const float4*)(b + c);
    ushort4 o;
    o.x = f2b((v.x - mu) * rr * gv.x + bv.x);
    o.y = f2b((v.y - mu) * rr * gv.y + bv.y);
    o.z = f2b((v.z - mu) * rr * gv.z + bv.z);
    o.w = f2b((v.w - mu) * rr * gv.w + bv.w);
    *(ushort4*)(out + row * 256 + c) = o;
}

// ---------------------------------------------------------------------------
// bf16 GEMM: C[M,N] = A[M,K] @ W[K,N], W pre-transposed as Bt[N,K].
// 128x128 tile, BK=32, 4 waves (2x2), 16x16x32 MFMA, global_load_lds staging.
// EPI: 0 = bias -> bf16 | 1 = (bias)*scale -> bf16 | 2 = gelu(bias) -> bf16
//      3 = bias + res -> fp32
// Requires M%128==0, N%128==0, K%32==0 (true for all calls here).
// ---------------------------------------------------------------------------
template <int EPI>
__global__ __launch_bounds__(256) void gemm128(const u16* __restrict__ A,
                                               const u16* __restrict__ Bt,
                                               const float* __restrict__ bias,
                                               const float* __restrict__ res,
                                               float scale, u16* outb, float* outf,
                                               int N, int K) {
    __shared__ u16 Alds[128 * 32];
    __shared__ u16 Blds[128 * 32];
    const int t = threadIdx.x;
    const int lane = t & 63;
    const int wave = t >> 6;
    const int wr = wave >> 1, wc = wave & 1;
    const int l15 = lane & 15, lg = lane >> 4;
    const long m0 = (long)blockIdx.x * 128;
    const int n0 = blockIdx.y * 128;

    const u16* Ag = A + (m0 + (t >> 2)) * K + (t & 3) * 8;
    const u16* Bg = Bt + (long)(n0 + (t >> 2)) * K + (t & 3) * 8;
    u16* Al = Alds + t * 8;
    u16* Bl = Blds + t * 8;

    f32x4 acc[4][4];
#pragma unroll
    for (int i = 0; i < 4; i++)
#pragma unroll
        for (int j = 0; j < 4; j++) acc[i][j] = (f32x4){0.f, 0.f, 0.f, 0.f};

    for (int k0 = 0; k0 < K; k0 += 32) {
        __syncthreads();
        __builtin_amdgcn_global_load_lds(GLB_AS(Ag + k0), LDS_AS(Al), 16, 0, 0);
        __builtin_amdgcn_global_load_lds(GLB_AS(Ag + (long)64 * K + k0), LDS_AS(Al + 2048), 16, 0, 0);
        __builtin_amdgcn_global_load_lds(GLB_AS(Bg + k0), LDS_AS(Bl), 16, 0, 0);
        __builtin_amdgcn_global_load_lds(GLB_AS(Bg + (long)64 * K + k0), LDS_AS(Bl + 2048), 16, 0, 0);
        __syncthreads();
        bf16x8 af[4], bfr[4];
#pragma unroll
        for (int i = 0; i < 4; i++)
            af[i] = *(const bf16x8*)(Alds + (wr * 64 + i * 16 + l15) * 32 + lg * 8);
#pragma unroll
        for (int i = 0; i < 4; i++)
            bfr[i] = *(const bf16x8*)(Blds + (wc * 64 + i * 16 + l15) * 32 + lg * 8);
#pragma unroll
        for (int mi = 0; mi < 4; mi++)
#pragma unroll
            for (int ni = 0; ni < 4; ni++)
                acc[mi][ni] = __builtin_amdgcn_mfma_f32_16x16x32_bf16(af[mi], bfr[ni], acc[mi][ni], 0, 0, 0);
    }

#pragma unroll
    for (int mi = 0; mi < 4; mi++) {
#pragma unroll
        for (int ni = 0; ni < 4; ni++) {
            const int col = n0 + wc * 64 + ni * 16 + l15;
            const float bv = bias[col];
#pragma unroll
            for (int r = 0; r < 4; r++) {
                const long row = m0 + wr * 64 + mi * 16 + lg * 4 + r;
                float v = acc[mi][ni][r] + bv;
                if (EPI == 1) v *= scale;
                if (EPI == 2) v = 0.5f * v * (1.f + erff(v * 0.70710678118f));
                const long idx = row * N + col;
                if (EPI == 3)
                    outf[idx] = v + res[idx];
                else
                    outb[idx] = f2b(v);
            }
        }
    }
}

// ---------------------------------------------------------------------------
// Windowed attention: one wave per (window, head). N=64 tokens, hd=32.
// Q pre-scaled. softmax(QK^T + bias) @ V, output at original token positions.
// ---------------------------------------------------------------------------
__global__ __launch_bounds__(256) void attn64(const u16* __restrict__ Q,
                                              const u16* __restrict__ KV,
                                              const float* __restrict__ Bm,
                                              u16* __restrict__ AO) {
    __shared__ u16 Plds[4][64 * 72];
    __shared__ u16 Vt[4][32 * 72];
    const int lane = threadIdx.x & 63, wave = threadIdx.x >> 6;
    const int wh = blockIdx.x * 4 + wave;  // 12800 total window-heads
    const int w = wh >> 3, h = wh & 7;
    const int b = w / 400, rem = w % 400;
    const int wy = rem / 20, wx = rem % 20;
    const long base_t = (long)b * 25600 + wy * 8 * 160 + wx * 8;
    const int l15 = lane & 15, lg = lane >> 4;

    // Q/K fragments straight from global: lane holds row (l&15), k-slice (l>>4)*8
    bf16x8 qf[4], kf[4];
#pragma unroll
    for (int ti = 0; ti < 4; ti++) {
        const int r = ti * 16 + l15;
        const long tt = base_t + (r >> 3) * 160 + (r & 7);
        qf[ti] = *(const bf16x8*)(Q + tt * 256 + h * 32 + lg * 8);
        kf[ti] = *(const bf16x8*)(KV + tt * 512 + h * 32 + lg * 8);
    }
    const f32x4 zz = (f32x4){0.f, 0.f, 0.f, 0.f};
    f32x4 s[4][4];
#pragma unroll
    for (int ti = 0; ti < 4; ti++)
#pragma unroll
        for (int tj = 0; tj < 4; tj++)
            s[ti][tj] = __builtin_amdgcn_mfma_f32_16x16x32_bf16(qf[ti], kf[tj], zz, 0, 0, 0);

    // stage V^T into LDS (Vt[col][k], padded stride 72)
    {
        const long tt = base_t + (lane >> 3) * 160 + (lane & 7);
        const u16* vrow = KV + tt * 512 + 256 + h * 32;
#pragma unroll
        for (int cg = 0; cg < 4; cg++) {
            bf16x8 v8 = *(const bf16x8*)(vrow + cg * 8);
#pragma unroll
            for (int j = 0; j < 8; j++) Vt[wave][(cg * 8 + j) * 72 + lane] = (u16)v8[j];
        }
    }

    // softmax rows: lane holds rows ti*16 + lg*4 + r, cols tj*16 + l15
    const float* Bh = Bm + h * 4096;
#pragma unroll
    for (int ti = 0; ti < 4; ti++) {
#pragma unroll
        for (int r = 0; r < 4; r++) {
            const int i = ti * 16 + lg * 4 + r;
            float vv[4];
            float m = -1e30f;
#pragma unroll
            for (int tj = 0; tj < 4; tj++) {
                vv[tj] = s[ti][tj][r] + Bh[i * 64 + tj * 16 + l15];
                m = fmaxf(m, vv[tj]);
            }
#pragma unroll
            for (int off = 1; off < 16; off <<= 1) m = fmaxf(m, __shfl_xor(m, off));
            float sum = 0.f;
#pragma unroll
            for (int tj = 0; tj < 4; tj++) {
                vv[tj] = __expf(vv[tj] - m);
                sum += vv[tj];
            }
#pragma unroll
            for (int off = 1; off < 16; off <<= 1) sum += __shfl_xor(sum, off);
            const float inv = 1.f / sum;
#pragma unroll
            for (int tj = 0; tj < 4; tj++)
                Plds[wave][i * 72 + tj * 16 + l15] = f2b(vv[tj] * inv);
        }
    }

    // PV: O[64,32] = P[64,64] @ V[64,32]
    f32x4 o[4][2];
#pragma unroll
    for (int mi = 0; mi < 4; mi++)
#pragma unroll
        for (int n = 0; n < 2; n++) o[mi][n] = zz;
#pragma unroll
    for (int c = 0; c < 2; c++) {
        bf16x8 vf[2];
#pragma unroll
        for (int n = 0; n < 2; n++)
            vf[n] = *(const bf16x8*)(&Vt[wave][(n * 16 + l15) * 72 + c * 32 + lg * 8]);
#pragma unroll
        for (int mi = 0; mi < 4; mi++) {
            bf16x8 pf = *(const bf16x8*)(&Plds[wave][(mi * 16 + l15) * 72 + c * 32 + lg * 8]);
#pragma unroll
            for (int n = 0; n < 2; n++)
                o[mi][n] = __builtin_amdgcn_mfma_f32_16x16x32_bf16(pf, vf[n], o[mi][n], 0, 0, 0);
        }
    }
#pragma unroll
    for (int mi = 0; mi < 4; mi++) {
#pragma unroll
        for (int n = 0; n < 2; n++) {
#pragma unroll
            for (int r = 0; r < 4; r++) {
                const int i = mi * 16 + lg * 4 + r;
                const long tt = base_t + (i >> 3) * 160 + (i & 7);
                AO[tt * 256 + h * 32 + n * 16 + l15] = f2b(o[mi][n][r]);
            }
        }
    }
}

// ---------------------------------------------------------------------------
extern "C" void kernel_launch(void* const* d_in, const int* in_sizes, int n_in,
                              void* d_out, int out_size, void* d_ws, size_t ws_size,
                              hipStream_t stream) {
    const float* x    = (const float*)d_in[0];
    const float* enc  = (const float*)d_in[1];
    const float* n1g  = (const float*)d_in[3];
    const float* n1b  = (const float*)d_in[4];
    const float* q1w  = (const float*)d_in[5];
    const float* q1b  = (const float*)d_in[6];
    const float* kv1w = (const float*)d_in[7];
    const float* kv1b = (const float*)d_in[8];
    const float* bias1 = (const float*)d_in[9];
    const float* p1w  = (const float*)d_in[10];
    const float* p1b  = (const float*)d_in[11];
    const float* q2w  = (const float*)d_in[12];
    const float* q2b  = (const float*)d_in[13];
    const float* kv2w = (const float*)d_in[14];
    const float* kv2b = (const float*)d_in[15];
    const float* bias2 = (const float*)d_in[16];
    const float* p2w  = (const float*)d_in[17];
    const float* p2b  = (const float*)d_in[18];
    const float* n2g  = (const float*)d_in[19];
    const float* n2b  = (const float*)d_in[20];
    const float* f1w  = (const float*)d_in[21];
    const float* f1b  = (const float*)d_in[22];
    const float* f2w  = (const float*)d_in[23];
    const float* f2bias = (const float*)d_in[24];
    float* out = (float*)d_out;

    char* ws = (char*)d_ws;
    size_t off = 0;
    auto alloc = [&](size_t bytes) {
        char* p = ws + off;
        off += (bytes + 255) & ~(size_t)255;
        return p;
    };
    u16* Wt   = (u16*)alloc(1048576 * 2);      // all transposed bf16 weights
    float* Bm = (float*)alloc(16 * 4096 * 4);  // [2][8][64][64] bias matrices
    u16* xn   = (u16*)alloc(52428800);         // LN1 out; reused for y1
    u16* qb   = (u16*)alloc(52428800);         // Q1; Q2; LN2 out
    u16* kvb  = (u16*)alloc(104857600);        // KV1; KV2
    u16* ao   = (u16*)alloc(52428800);         // attn out 1; 2
    u16* encb = (u16*)alloc(52428800);         // enc_feat bf16
    u16* h1   = (u16*)alloc(52428800);         // MLP hidden (chunked)

    u16 *q1t = Wt, *kv1t = Wt + 65536, *p1t = Wt + 196608, *q2t = Wt + 262144,
        *kv2t = Wt + 327680, *p2t = Wt + 458752, *f1t = Wt + 524288, *f2t = Wt + 786432;

    PrepAll pa;
    pa.src[0] = q1w;  pa.dst[0] = q1t;  pa.K[0] = 256;  pa.N[0] = 256;
    pa.src[1] = kv1w; pa.dst[1] = kv1t; pa.K[1] = 256;  pa.N[1] = 512;
    pa.src[2] = p1w;  pa.dst[2] = p1t;  pa.K[2] = 256;  pa.N[2] = 256;
    pa.src[3] = q2w;  pa.dst[3] = q2t;  pa.K[3] = 256;  pa.N[3] = 256;
    pa.src[4] = kv2w; pa.dst[4] = kv2t; pa.K[4] = 256;  pa.N[4] = 512;
    pa.src[5] = p2w;  pa.dst[5] = p2t;  pa.K[5] = 256;  pa.N[5] = 256;
    pa.src[6] = f1w;  pa.dst[6] = f1t;  pa.K[6] = 256;  pa.N[6] = 1024;
    pa.src[7] = f2w;  pa.dst[7] = f2t;  pa.K[7] = 1024; pa.N[7] = 256;
    prep_w<<<dim3(1024, 8), 256, 0, stream>>>(pa);
    prep_bias<<<dim3(64, 16), 64, 0, stream>>>(bias1, bias2, Bm);
    cast_bf<<<dim3(12800), 256, 0, stream>>>(enc, encb);
    ln256<<<dim3(25600), 256, 0, stream>>>(x, n1g, n1b, xn);

    const float qscale = 0.17677669529663687f;  // 32^-0.5

    // stage 1: self-attention on LN(x)
    gemm128<1><<<dim3(800, 2), 256, 0, stream>>>(xn, q1t, q1b, nullptr, qscale, qb, nullptr, 256, 256);
    gemm128<0><<<dim3(800, 4), 256, 0, stream>>>(xn, kv1t, kv1b, nullptr, 1.f, kvb, nullptr, 512, 256);
    attn64<<<dim3(3200), 256, 0, stream>>>(qb, kvb, Bm, ao);
    gemm128<0><<<dim3(800, 2), 256, 0, stream>>>(ao, p1t, p1b, nullptr, 1.f, xn, nullptr, 256, 256);

    // stage 2: cross-attention to enc_feat
    gemm128<1><<<dim3(800, 2), 256, 0, stream>>>(xn, q2t, q2b, nullptr, qscale, qb, nullptr, 256, 256);
    gemm128<0><<<dim3(800, 4), 256, 0, stream>>>(encb, kv2t, kv2b, nullptr, 1.f, kvb, nullptr, 512, 256);
    attn64<<<dim3(3200), 256, 0, stream>>>(qb, kvb, Bm + 8 * 4096, ao);

    // proj2 + shortcut residual -> x2 in d_out (fp32)
    gemm128<3><<<dim3(800, 2), 256, 0, stream>>>(ao, p2t, p2b, x, 1.f, (u16*)nullptr, out, 256, 256);

    // MLP: LN2 -> fc1+gelu -> fc2 + residual (in-place on d_out), 4 row-chunks
    ln256<<<dim3(25600), 256, 0, stream>>>(out, n2g, n2b, qb);
    for (int c = 0; c < 4; c++) {
        const u16* xh = qb + (size_t)c * 25600 * 256;
        float* oc = out + (size_t)c * 25600 * 256;
        gemm128<2><<<dim3(200, 8), 256, 0, stream>>>(xh, f1t, f1b, nullptr, 1.f, h1, nullptr, 1024, 256);
        gemm128<3><<<dim3(200, 2), 256, 0, stream>>>(h1, f2t, f2bias, oc, 1.f, (u16*)nullptr, oc, 256, 1024);
    }
}

// Round 2
// 800.925 us; speedup vs baseline: 1.1666x; 1.1666x over previous
//
#include <hip/hip_runtime.h>

typedef __attribute__((ext_vector_type(4))) float f32x4;
typedef __attribute__((ext_vector_type(8))) short bf16x8;
typedef __attribute__((ext_vector_type(8))) unsigned short ushort8;
typedef unsigned short u16;
typedef unsigned int u32;

#define LDS_AS(p) ((__attribute__((address_space(3))) void*)(p))
#define GLB_AS(p) ((const __attribute__((address_space(1))) void*)(p))

__device__ __forceinline__ u16 f2b(float f) {
    u32 u = __builtin_bit_cast(u32, f);
    u32 r = (u + 0x7fffu + ((u >> 16) & 1u)) >> 16;
    return (u16)r;
}

// ---------------------------------------------------------------------------
// Weight prep: fp32 [K,N] -> bf16 [N,K] (transposed), optional scale
// ---------------------------------------------------------------------------
struct PrepAll {
    const float* src[8];
    u16* dst[8];
    int K[8];
    int N[8];
    float S[8];
};

__global__ __launch_bounds__(256) void prep_w(PrepAll p) {
    const int wi = blockIdx.y;
    const int K = p.K[wi], N = p.N[wi];
    const int e = blockIdx.x * 256 + threadIdx.x;
    if (e >= K * N) return;
    const int k = e / N, n = e % N;
    p.dst[wi][n * K + k] = f2b(p.src[wi][e] * p.S[wi]);
}

// Bm[s*8+h][i][j] = table_s[rel_idx(i,j)*8 + h], window 8x8
__global__ __launch_bounds__(64) void prep_bias(const float* __restrict__ t1,
                                                const float* __restrict__ t2,
                                                float* __restrict__ Bm) {
    const int j = threadIdx.x;
    const int i = blockIdx.x;
    const int hh = blockIdx.y;
    const int s = hh >> 3, h = hh & 7;
    const int idx = ((i >> 3) - (j >> 3) + 7) * 15 + ((i & 7) - (j & 7) + 7);
    const float* tab = s ? t2 : t1;
    Bm[(long)hh * 4096 + i * 64 + j] = tab[idx * 8 + h];
}

// b1cat[768] = [qs*q1b, kv1b]; q2bs[256] = qs*q2b
__global__ __launch_bounds__(256) void prep_bcat(const float* __restrict__ q1b,
                                                 const float* __restrict__ kv1b,
                                                 const float* __restrict__ q2b,
                                                 float qs, float* __restrict__ b1cat,
                                                 float* __restrict__ q2bs) {
    const int g = blockIdx.x * 256 + threadIdx.x;
    if (g < 256) {
        b1cat[g] = qs * q1b[g];
        q2bs[g] = qs * q2b[g];
    } else if (g < 768) {
        b1cat[g] = kv1b[g - 256];
    }
}

// fp32 -> bf16 cast, 8 elems/thread
__global__ __launch_bounds__(256) void cast_bf(const float* __restrict__ in,
                                               u16* __restrict__ out) {
    const long i = (long)blockIdx.x * 256 + threadIdx.x;
    const float4 a = *(const float4*)(in + i * 8);
    const float4 b = *(const float4*)(in + i * 8 + 4);
    ushort8 o;
    o[0] = f2b(a.x); o[1] = f2b(a.y); o[2] = f2b(a.z); o[3] = f2b(a.w);
    o[4] = f2b(b.x); o[5] = f2b(b.y); o[6] = f2b(b.z); o[7] = f2b(b.w);
    *(ushort8*)(out + i * 8) = o;
}

// ---------------------------------------------------------------------------
// LayerNorm over C=256, one wave per row, fp32 in -> bf16 out
// ---------------------------------------------------------------------------
__global__ __launch_bounds__(256) void ln256(const float* __restrict__ x,
                                             const float* __restrict__ g,
                                             const float* __restrict__ b,
                                             u16* __restrict__ out) {
    const int lane = threadIdx.x & 63;
    const long row = (long)blockIdx.x * 4 + (threadIdx.x >> 6);
    const float4 v = *(const float4*)(x + row * 256 + lane * 4);
    float s = v.x + v.y + v.z + v.w;
    float s2 = v.x * v.x + v.y * v.y + v.z * v.z + v.w * v.w;
#pragma unroll
    for (int off = 32; off > 0; off >>= 1) {
        s += __shfl_xor(s, off);
        s2 += __shfl_xor(s2, off);
    }
    const float mu = s * (1.f / 256.f);
    const float var = s2 * (1.f / 256.f) - mu * mu;
    const float rr = rsqrtf(var + 1e-5f);
    const int c = lane * 4;
    const float4 gv = *(const float4*)(g + c);
    const float4 bv = *(const float4*)(b + c);
    ushort4 o;
    o.x = f2b((v.x - mu) * rr * gv.x + bv.x);
    o.y = f2b((v.y - mu) * rr * gv.y + bv.y);
    o.z = f2b((v.z - mu) * rr * gv.z + bv.z);
    o.w = f2b((v.w - mu) * rr * gv.w + bv.w);
    *(ushort4*)(out + row * 256 + c) = o;
}

// ---------------------------------------------------------------------------
// Pipelined bf16 GEMM: C[M,N] = A[M,K] @ Bt[N,K]^T. 128x128 tile, BK=32,
// 4 waves, double-buffered LDS, counted vmcnt (never drain mid-loop),
// XCD-chunked block swizzle (grid must be 1-D with gridDim.x % 8 == 0).
// EPI: 0 = bias -> bf16 | 2 = gelu(bias) -> bf16 | 3 = bias + res -> fp32
// ---------------------------------------------------------------------------
template <int EPI>
__global__ __launch_bounds__(256) void gemm128(const u16* __restrict__ A,
                                               const u16* __restrict__ Bt,
                                               const float* __restrict__ bias,
                                               const float* __restrict__ res,
                                               u16* outb, float* outf,
                                               int N, int K, int Nt) {
    __shared__ u16 lds[2][2][128 * 32];
    const int t = threadIdx.x;
    const int lane = t & 63;
    const int wave = t >> 6;
    const int wr = wave >> 1, wc = wave & 1;
    const int l15 = lane & 15, lg = lane >> 4;

    // XCD-chunked swizzle: each XCD gets contiguous (m,n) ids, n-fastest.
    const int per = gridDim.x >> 3;
    const int id2 = (blockIdx.x & 7) * per + (blockIdx.x >> 3);
    const int bm = id2 / Nt, bn = id2 % Nt;
    const long m0 = (long)bm * 128;
    const int n0 = bn * 128;

    const u16* Ag = A + (m0 + (t >> 2)) * K + (t & 3) * 8;
    const u16* Bg = Bt + (long)(n0 + (t >> 2)) * K + (t & 3) * 8;

    const int nt = K >> 5;

    auto stage = [&](int b, int k0) {
        u16* Al = lds[b][0] + t * 8;
        u16* Bl = lds[b][1] + t * 8;
        __builtin_amdgcn_global_load_lds(GLB_AS(Ag + k0), LDS_AS(Al), 16, 0, 0);
        __builtin_amdgcn_global_load_lds(GLB_AS(Ag + (long)64 * K + k0), LDS_AS(Al + 2048), 16, 0, 0);
        __builtin_amdgcn_global_load_lds(GLB_AS(Bg + k0), LDS_AS(Bl), 16, 0, 0);
        __builtin_amdgcn_global_load_lds(GLB_AS(Bg + (long)64 * K + k0), LDS_AS(Bl + 2048), 16, 0, 0);
    };

    f32x4 acc[4][4];
#pragma unroll
    for (int i = 0; i < 4; i++)
#pragma unroll
        for (int j = 0; j < 4; j++) acc[i][j] = (f32x4){0.f, 0.f, 0.f, 0.f};

    stage(0, 0);
    if (nt > 1) stage(1, 32);

    for (int tt = 0; tt < nt; ++tt) {
        const int cur = tt & 1;
        // wait for tile tt's 4 loads (leave tile tt+1's 4 in flight)
        if (tt < nt - 1)
            asm volatile("s_waitcnt vmcnt(4)" ::: "memory");
        else
            asm volatile("s_waitcnt vmcnt(0)" ::: "memory");
        __builtin_amdgcn_s_barrier();

        bf16x8 af[4], bfr[4];
#pragma unroll
        for (int i = 0; i < 4; i++)
            af[i] = *(const bf16x8*)(lds[cur][0] + (wr * 64 + i * 16 + l15) * 32 + lg * 8);
#pragma unroll
        for (int i = 0; i < 4; i++)
            bfr[i] = *(const bf16x8*)(lds[cur][1] + (wc * 64 + i * 16 + l15) * 32 + lg * 8);
        asm volatile("s_waitcnt lgkmcnt(0)" ::: "memory");
        __builtin_amdgcn_sched_barrier(0);
        __builtin_amdgcn_s_barrier();  // all waves done reading lds[cur]

        if (tt + 2 < nt) stage(cur, (tt + 2) * 32);  // overwrite freed buffer

#pragma unroll
        for (int mi = 0; mi < 4; mi++)
#pragma unroll
            for (int ni = 0; ni < 4; ni++)
                acc[mi][ni] = __builtin_amdgcn_mfma_f32_16x16x32_bf16(af[mi], bfr[ni], acc[mi][ni], 0, 0, 0);
    }

#pragma unroll
    for (int mi = 0; mi < 4; mi++) {
#pragma unroll
        for (int ni = 0; ni < 4; ni++) {
            const int col = n0 + wc * 64 + ni * 16 + l15;
            const float bv = bias[col];
#pragma unroll
            for (int r = 0; r < 4; r++) {
                const long row = m0 + wr * 64 + mi * 16 + lg * 4 + r;
                float v = acc[mi][ni][r] + bv;
                if (EPI == 2) v = 0.5f * v * (1.f + erff(v * 0.70710678118f));
                const long idx = row * N + col;
                if (EPI == 3)
                    outf[idx] = v + res[idx];
                else
                    outb[idx] = f2b(v);
            }
        }
    }
}

// ---------------------------------------------------------------------------
// Windowed attention: one wave per (window, head). N=64 tokens, hd=32.
// Q pre-scaled. softmax(QK^T + bias) @ V. Strides parameterized so the fused
// QKV buffer (stride 768) and split buffers (256/512) both work.
// ---------------------------------------------------------------------------
__global__ __launch_bounds__(256) void attn64(const u16* __restrict__ Q, int qs,
                                              const u16* __restrict__ KV, int ks,
                                              const float* __restrict__ Bm,
                                              u16* __restrict__ AO) {
    __shared__ u16 Plds[4][64 * 72];
    __shared__ u16 Vt[4][32 * 72];
    const int lane = threadIdx.x & 63, wave = threadIdx.x >> 6;
    const int wh = blockIdx.x * 4 + wave;
    const int w = wh >> 3, h = wh & 7;
    const int b = w / 400, rem = w % 400;
    const int wy = rem / 20, wx = rem % 20;
    const long base_t = (long)b * 25600 + wy * 8 * 160 + wx * 8;
    const int l15 = lane & 15, lg = lane >> 4;

    bf16x8 qf[4], kf[4];
#pragma unroll
    for (int ti = 0; ti < 4; ti++) {
        const int r = ti * 16 + l15;
        const long tt = base_t + (r >> 3) * 160 + (r & 7);
        qf[ti] = *(const bf16x8*)(Q + tt * qs + h * 32 + lg * 8);
        kf[ti] = *(const bf16x8*)(KV + tt * ks + h * 32 + lg * 8);
    }
    const f32x4 zz = (f32x4){0.f, 0.f, 0.f, 0.f};
    f32x4 s[4][4];
#pragma unroll
    for (int ti = 0; ti < 4; ti++)
#pragma unroll
        for (int tj = 0; tj < 4; tj++)
            s[ti][tj] = __builtin_amdgcn_mfma_f32_16x16x32_bf16(qf[ti], kf[tj], zz, 0, 0, 0);

    {
        const long tt = base_t + (lane >> 3) * 160 + (lane & 7);
        const u16* vrow = KV + tt * ks + 256 + h * 32;
#pragma unroll
        for (int cg = 0; cg < 4; cg++) {
            bf16x8 v8 = *(const bf16x8*)(vrow + cg * 8);
#pragma unroll
            for (int j = 0; j < 8; j++) Vt[wave][(cg * 8 + j) * 72 + lane] = (u16)v8[j];
        }
    }

    const float* Bh = Bm + h * 4096;
#pragma unroll
    for (int ti = 0; ti < 4; ti++) {
#pragma unroll
        for (int r = 0; r < 4; r++) {
            const int i = ti * 16 + lg * 4 + r;
            float vv[4];
            float m = -1e30f;
#pragma unroll
            for (int tj = 0; tj < 4; tj++) {
                vv[tj] = s[ti][tj][r] + Bh[i * 64 + tj * 16 + l15];
                m = fmaxf(m, vv[tj]);
            }
#pragma unroll
            for (int off = 1; off < 16; off <<= 1) m = fmaxf(m, __shfl_xor(m, off));
            float sum = 0.f;
#pragma unroll
            for (int tj = 0; tj < 4; tj++) {
                vv[tj] = __expf(vv[tj] - m);
                sum += vv[tj];
            }
#pragma unroll
            for (int off = 1; off < 16; off <<= 1) sum += __shfl_xor(sum, off);
            const float inv = 1.f / sum;
#pragma unroll
            for (int tj = 0; tj < 4; tj++)
                Plds[wave][i * 72 + tj * 16 + l15] = f2b(vv[tj] * inv);
        }
    }

    f32x4 o[4][2];
#pragma unroll
    for (int mi = 0; mi < 4; mi++)
#pragma unroll
        for (int n = 0; n < 2; n++) o[mi][n] = zz;
#pragma unroll
    for (int c = 0; c < 2; c++) {
        bf16x8 vf[2];
#pragma unroll
        for (int n = 0; n < 2; n++)
            vf[n] = *(const bf16x8*)(&Vt[wave][(n * 16 + l15) * 72 + c * 32 + lg * 8]);
#pragma unroll
        for (int mi = 0; mi < 4; mi++) {
            bf16x8 pf = *(const bf16x8*)(&Plds[wave][(mi * 16 + l15) * 72 + c * 32 + lg * 8]);
#pragma unroll
            for (int n = 0; n < 2; n++)
                o[mi][n] = __builtin_amdgcn_mfma_f32_16x16x32_bf16(pf, vf[n], o[mi][n], 0, 0, 0);
        }
    }
#pragma unroll
    for (int mi = 0; mi < 4; mi++) {
#pragma unroll
        for (int n = 0; n < 2; n++) {
#pragma unroll
            for (int r = 0; r < 4; r++) {
                const int i = mi * 16 + lg * 4 + r;
                const long tt = base_t + (i >> 3) * 160 + (i & 7);
                AO[tt * 256 + h * 32 + n * 16 + l15] = f2b(o[mi][n][r]);
            }
        }
    }
}

// ---------------------------------------------------------------------------
extern "C" void kernel_launch(void* const* d_in, const int* in_sizes, int n_in,
                              void* d_out, int out_size, void* d_ws, size_t ws_size,
                              hipStream_t stream) {
    const float* x    = (const float*)d_in[0];
    const float* enc  = (const float*)d_in[1];
    const float* n1g  = (const float*)d_in[3];
    const float* n1b  = (const float*)d_in[4];
    const float* q1w  = (const float*)d_in[5];
    const float* q1b  = (const float*)d_in[6];
    const float* kv1w = (const float*)d_in[7];
    const float* kv1b = (const float*)d_in[8];
    const float* bias1 = (const float*)d_in[9];
    const float* p1w  = (const float*)d_in[10];
    const float* p1b  = (const float*)d_in[11];
    const float* q2w  = (const float*)d_in[12];
    const float* q2b  = (const float*)d_in[13];
    const float* kv2w = (const float*)d_in[14];
    const float* kv2b = (const float*)d_in[15];
    const float* bias2 = (const float*)d_in[16];
    const float* p2w  = (const float*)d_in[17];
    const float* p2b  = (const float*)d_in[18];
    const float* n2g  = (const float*)d_in[19];
    const float* n2b  = (const float*)d_in[20];
    const float* f1w  = (const float*)d_in[21];
    const float* f1b  = (const float*)d_in[22];
    const float* f2w  = (const float*)d_in[23];
    const float* f2bias = (const float*)d_in[24];
    float* out = (float*)d_out;

    char* ws = (char*)d_ws;
    size_t off = 0;
    auto alloc = [&](size_t bytes) {
        char* p = ws + off;
        off += (bytes + 255) & ~(size_t)255;
        return p;
    };
    u16* Wt    = (u16*)alloc(1048576 * 2);
    float* Bm  = (float*)alloc(16 * 4096 * 4);
    float* b1c = (float*)alloc(768 * 4);
    float* q2s = (float*)alloc(256 * 4);
    u16* xn    = (u16*)alloc(52428800);   // LN1 out; then y1
    u16* qb    = (u16*)alloc(52428800);   // qkv part 1 / Q2 / LN2 out
    u16* kvb   = (u16*)alloc(104857600);  // qkv part 2 / KV2 / MLP hidden
    u16* ao    = (u16*)alloc(52428800);   // attn out (+ h1 overflow)
    u16* encb  = (u16*)alloc(52428800);   // enc_feat bf16

    u16* qkv = qb;       // [102400][768]: qb+kvb contiguous (157.3 MB)
    u16* h1  = kvb;      // MLP hidden chunk [51200][1024] (kvb+ao region)

    u16 *q1t = Wt, *p1t = Wt + 196608, *q2t = Wt + 262144,
        *kv2t = Wt + 327680, *p2t = Wt + 458752, *f1t = Wt + 524288, *f2t = Wt + 786432;

    const float qscale = 0.17677669529663687f;  // 32^-0.5

    PrepAll pa;
    pa.src[0] = q1w;  pa.dst[0] = q1t;          pa.K[0] = 256;  pa.N[0] = 256;  pa.S[0] = qscale;
    pa.src[1] = kv1w; pa.dst[1] = Wt + 65536;   pa.K[1] = 256;  pa.N[1] = 512;  pa.S[1] = 1.f;
    pa.src[2] = p1w;  pa.dst[2] = p1t;          pa.K[2] = 256;  pa.N[2] = 256;  pa.S[2] = 1.f;
    pa.src[3] = q2w;  pa.dst[3] = q2t;          pa.K[3] = 256;  pa.N[3] = 256;  pa.S[3] = qscale;
    pa.src[4] = kv2w; pa.dst[4] = kv2t;         pa.K[4] = 256;  pa.N[4] = 512;  pa.S[4] = 1.f;
    pa.src[5] = p2w;  pa.dst[5] = p2t;          pa.K[5] = 256;  pa.N[5] = 256;  pa.S[5] = 1.f;
    pa.src[6] = f1w;  pa.dst[6] = f1t;          pa.K[6] = 256;  pa.N[6] = 1024; pa.S[6] = 1.f;
    pa.src[7] = f2w;  pa.dst[7] = f2t;          pa.K[7] = 1024; pa.N[7] = 256;  pa.S[7] = 1.f;
    prep_w<<<dim3(1024, 8), 256, 0, stream>>>(pa);
    prep_bias<<<dim3(64, 16), 64, 0, stream>>>(bias1, bias2, Bm);
    prep_bcat<<<dim3(3), 256, 0, stream>>>(q1b, kv1b, q2b, qscale, b1c, q2s);
    cast_bf<<<dim3(12800), 256, 0, stream>>>(enc, encb);
    ln256<<<dim3(25600), 256, 0, stream>>>(x, n1g, n1b, xn);

    // stage 1: fused QKV gemm (Q pre-scaled in weights/bias), then attn, proj
    gemm128<0><<<dim3(4800), 256, 0, stream>>>(xn, q1t, b1c, nullptr, qkv, nullptr, 768, 256, 6);
    attn64<<<dim3(3200), 256, 0, stream>>>(qkv, 768, qkv + 256, 768, Bm, ao);
    gemm128<0><<<dim3(1600), 256, 0, stream>>>(ao, p1t, p1b, nullptr, xn, nullptr, 256, 256, 2);

    // stage 2: cross-attention to encoder features
    gemm128<0><<<dim3(1600), 256, 0, stream>>>(xn, q2t, q2s, nullptr, qb, nullptr, 256, 256, 2);
    gemm128<0><<<dim3(3200), 256, 0, stream>>>(encb, kv2t, kv2b, nullptr, kvb, nullptr, 512, 256, 4);
    attn64<<<dim3(3200), 256, 0, stream>>>(qb, 256, kvb, 512, Bm + 8 * 4096, ao);

    // proj2 + shortcut residual -> fp32 in d_out
    gemm128<3><<<dim3(1600), 256, 0, stream>>>(ao, p2t, p2b, x, (u16*)nullptr, out, 256, 256, 2);

    // MLP: LN2 -> fc1+gelu -> fc2+residual (in-place), 2 row-chunks
    ln256<<<dim3(25600), 256, 0, stream>>>(out, n2g, n2b, qb);
    for (int c = 0; c < 2; c++) {
        const u16* xh = qb + (size_t)c * 51200 * 256;
        float* oc = out + (size_t)c * 51200 * 256;
        gemm128<2><<<dim3(3200), 256, 0, stream>>>(xh, f1t, f1b, nullptr, h1, nullptr, 1024, 256, 8);
        gemm128<3><<<dim3(800), 256, 0, stream>>>(h1, f2t, f2bias, oc, (u16*)nullptr, oc, 256, 1024, 2);
    }
}

// Round 3
// 794.344 us; speedup vs baseline: 1.1763x; 1.0083x over previous
//
#include <hip/hip_runtime.h>

typedef __attribute__((ext_vector_type(4))) float f32x4;
typedef __attribute__((ext_vector_type(8))) short bf16x8;
typedef __attribute__((ext_vector_type(8))) unsigned short ushort8;
typedef unsigned short u16;
typedef unsigned int u32;

__device__ __forceinline__ u16 f2b(float f) {
    u32 u = __builtin_bit_cast(u32, f);
    u32 r = (u + 0x7fffu + ((u >> 16) & 1u)) >> 16;
    return (u16)r;
}

// ---------------------------------------------------------------------------
// Weight prep: fp32 [K,N] -> bf16 [N,K] (transposed), optional scale
// ---------------------------------------------------------------------------
struct PrepAll {
    const float* src[8];
    u16* dst[8];
    int K[8];
    int N[8];
    float S[8];
};

__global__ __launch_bounds__(256) void prep_w(PrepAll p) {
    const int wi = blockIdx.y;
    const int K = p.K[wi], N = p.N[wi];
    const int e = blockIdx.x * 256 + threadIdx.x;
    if (e >= K * N) return;
    const int k = e / N, n = e % N;
    p.dst[wi][n * K + k] = f2b(p.src[wi][e] * p.S[wi]);
}

__global__ __launch_bounds__(64) void prep_bias(const float* __restrict__ t1,
                                                const float* __restrict__ t2,
                                                float* __restrict__ Bm) {
    const int j = threadIdx.x;
    const int i = blockIdx.x;
    const int hh = blockIdx.y;
    const int s = hh >> 3, h = hh & 7;
    const int idx = ((i >> 3) - (j >> 3) + 7) * 15 + ((i & 7) - (j & 7) + 7);
    const float* tab = s ? t2 : t1;
    Bm[(long)hh * 4096 + i * 64 + j] = tab[idx * 8 + h];
}

__global__ __launch_bounds__(256) void prep_bcat(const float* __restrict__ q1b,
                                                 const float* __restrict__ kv1b,
                                                 const float* __restrict__ q2b,
                                                 float qs, float* __restrict__ b1cat,
                                                 float* __restrict__ q2bs) {
    const int g = blockIdx.x * 256 + threadIdx.x;
    if (g < 256) {
        b1cat[g] = qs * q1b[g];
        q2bs[g] = qs * q2b[g];
    } else if (g < 768) {
        b1cat[g] = kv1b[g - 256];
    }
}

__global__ __launch_bounds__(256) void cast_bf(const float* __restrict__ in,
                                               u16* __restrict__ out) {
    const long i = (long)blockIdx.x * 256 + threadIdx.x;
    const float4 a = *(const float4*)(in + i * 8);
    const float4 b = *(const float4*)(in + i * 8 + 4);
    ushort8 o;
    o[0] = f2b(a.x); o[1] = f2b(a.y); o[2] = f2b(a.z); o[3] = f2b(a.w);
    o[4] = f2b(b.x); o[5] = f2b(b.y); o[6] = f2b(b.z); o[7] = f2b(b.w);
    *(ushort8*)(out + i * 8) = o;
}

__global__ __launch_bounds__(256) void ln256(const float* __restrict__ x,
                                             const float* __restrict__ g,
                                             const float* __restrict__ b,
                                             u16* __restrict__ out) {
    const int lane = threadIdx.x & 63;
    const long row = (long)blockIdx.x * 4 + (threadIdx.x >> 6);
    const float4 v = *(const float4*)(x + row * 256 + lane * 4);
    float s = v.x + v.y + v.z + v.w;
    float s2 = v.x * v.x + v.y * v.y + v.z * v.z + v.w * v.w;
#pragma unroll
    for (int off = 32; off > 0; off >>= 1) {
        s += __shfl_xor(s, off);
        s2 += __shfl_xor(s2, off);
    }
    const float mu = s * (1.f / 256.f);
    const float var = s2 * (1.f / 256.f) - mu * mu;
    const float rr = rsqrtf(var + 1e-5f);
    const int c = lane * 4;
    const float4 gv = *(const float4*)(g + c);
    const float4 bv = *(const float4*)(b + c);
    ushort4 o;
    o.x = f2b((v.x - mu) * rr * gv.x + bv.x);
    o.y = f2b((v.y - mu) * rr * gv.y + bv.y);
    o.z = f2b((v.z - mu) * rr * gv.z + bv.z);
    o.w = f2b((v.w - mu) * rr * gv.w + bv.w);
    *(ushort4*)(out + row * 256 + c) = o;
}

// ---------------------------------------------------------------------------
// Reg-staged pipelined bf16 GEMM: C[M,N] = A[M,K] @ Bt[N,K]^T.
// 128x128 tile, BK=32, 4 waves. global->VGPR->ds_write (compiler emits exact
// counted vmcnt), 3 reg-sets (2+ iters of load slack), double-buffered LDS,
// one raw s_barrier per K-step, padded LDS stride (40 u16) for conflict-free
// ds_read_b128. K-loop fully unrolled (NT = K/32 template param).
// EPI: 0 = bias -> bf16 | 2 = gelu(bias) -> bf16 | 3 = bias + res -> fp32
// ---------------------------------------------------------------------------
#define LSTR 40

template <int EPI, int NT>
__global__ __launch_bounds__(256, 3) void gemmP(const u16* __restrict__ A,
                                                const u16* __restrict__ Bt,
                                                const float* __restrict__ bias,
                                                const float* __restrict__ res,
                                                u16* outb, float* outf,
                                                int N, int Nt) {
    constexpr int K = NT * 32;
    __shared__ u16 ldsA[2][128 * LSTR];
    __shared__ u16 ldsB[2][128 * LSTR];
    const int t = threadIdx.x;
    const int lane = t & 63;
    const int wave = t >> 6;
    const int wr = wave >> 1, wc = wave & 1;
    const int l15 = lane & 15, lg = lane >> 4;

    // XCD-chunked swizzle (grid 1-D, gridDim.x % 8 == 0), n-fastest within XCD
    const int per = gridDim.x >> 3;
    const int id2 = (blockIdx.x & 7) * per + (blockIdx.x >> 3);
    const int bm = id2 / Nt, bn = id2 % Nt;
    const long m0 = (long)bm * 128;
    const int n0 = bn * 128;

    const int srow = t >> 2, skc = (t & 3) * 8;  // staging coords
    const u16* Ag = A + (m0 + srow) * K + skc;
    const u16* Bg = Bt + (long)(n0 + srow) * K + skc;

    bf16x8 ra[3][2], rb[3][2];

#define LOAD_TILE(s, kt)                                            \
    do {                                                            \
        ra[s][0] = *(const bf16x8*)(Ag + (kt) * 32);                \
        ra[s][1] = *(const bf16x8*)(Ag + (long)64 * K + (kt) * 32); \
        rb[s][0] = *(const bf16x8*)(Bg + (kt) * 32);                \
        rb[s][1] = *(const bf16x8*)(Bg + (long)64 * K + (kt) * 32); \
    } while (0)

#define WRITE_TILE(s, buf)                                              \
    do {                                                                \
        *(bf16x8*)&ldsA[buf][srow * LSTR + skc] = ra[s][0];             \
        *(bf16x8*)&ldsA[buf][(srow + 64) * LSTR + skc] = ra[s][1];      \
        *(bf16x8*)&ldsB[buf][srow * LSTR + skc] = rb[s][0];             \
        *(bf16x8*)&ldsB[buf][(srow + 64) * LSTR + skc] = rb[s][1];      \
    } while (0)

    f32x4 acc[4][4];
#pragma unroll
    for (int i = 0; i < 4; i++)
#pragma unroll
        for (int j = 0; j < 4; j++) acc[i][j] = (f32x4){0.f, 0.f, 0.f, 0.f};

    // prologue: 3 tiles in flight, tile 0 written to LDS buf 0
    LOAD_TILE(0, 0);
    if (NT > 1) LOAD_TILE(1, 1);
    if (NT > 2) LOAD_TILE(2, 2);
    WRITE_TILE(0, 0);  // compiler emits vmcnt(8) here (only set 0 needed)
    asm volatile("s_waitcnt lgkmcnt(0)" ::: "memory");
    __builtin_amdgcn_s_barrier();
    __builtin_amdgcn_sched_barrier(0);

#pragma unroll
    for (int tt = 0; tt < NT; ++tt) {
        const int cur = tt & 1;
        bf16x8 af[4], bfr[4];
#pragma unroll
        for (int i = 0; i < 4; i++)
            af[i] = *(const bf16x8*)&ldsA[cur][(wr * 64 + i * 16 + l15) * LSTR + lg * 8];
#pragma unroll
        for (int i = 0; i < 4; i++)
            bfr[i] = *(const bf16x8*)&ldsB[cur][(wc * 64 + i * 16 + l15) * LSTR + lg * 8];

        if (tt + 3 < NT) LOAD_TILE(tt % 3, tt + 3);          // refill freed set
        if (tt + 1 < NT) WRITE_TILE((tt + 1) % 3, 1 - cur);  // vmcnt counted by compiler

#pragma unroll
        for (int mi = 0; mi < 4; mi++)
#pragma unroll
            for (int ni = 0; ni < 4; ni++)
                acc[mi][ni] = __builtin_amdgcn_mfma_f32_16x16x32_bf16(af[mi], bfr[ni], acc[mi][ni], 0, 0, 0);

        if (tt + 1 < NT) {
            asm volatile("s_waitcnt lgkmcnt(0)" ::: "memory");
            __builtin_amdgcn_s_barrier();
            __builtin_amdgcn_sched_barrier(0);
        }
    }
#undef LOAD_TILE
#undef WRITE_TILE

#pragma unroll
    for (int mi = 0; mi < 4; mi++) {
#pragma unroll
        for (int ni = 0; ni < 4; ni++) {
            const int col = n0 + wc * 64 + ni * 16 + l15;
            const float bv = bias[col];
#pragma unroll
            for (int r = 0; r < 4; r++) {
                const long row = m0 + wr * 64 + mi * 16 + lg * 4 + r;
                float v = acc[mi][ni][r] + bv;
                if (EPI == 2) v = 0.5f * v * (1.f + erff(v * 0.70710678118f));
                const long idx = row * N + col;
                if (EPI == 3)
                    outf[idx] = v + res[idx];
                else
                    outb[idx] = f2b(v);
            }
        }
    }
}

// ---------------------------------------------------------------------------
// Windowed attention: one wave per (window, head). N=64 tokens, hd=32.
// ---------------------------------------------------------------------------
__global__ __launch_bounds__(256) void attn64(const u16* __restrict__ Q, int qs,
                                              const u16* __restrict__ KV, int ks,
                                              const float* __restrict__ Bm,
                                              u16* __restrict__ AO) {
    __shared__ u16 Plds[4][64 * 72];
    __shared__ u16 Vt[4][32 * 72];
    const int lane = threadIdx.x & 63, wave = threadIdx.x >> 6;
    const int wh = blockIdx.x * 4 + wave;
    const int w = wh >> 3, h = wh & 7;
    const int b = w / 400, rem = w % 400;
    const int wy = rem / 20, wx = rem % 20;
    const long base_t = (long)b * 25600 + wy * 8 * 160 + wx * 8;
    const int l15 = lane & 15, lg = lane >> 4;

    bf16x8 qf[4], kf[4];
#pragma unroll
    for (int ti = 0; ti < 4; ti++) {
        const int r = ti * 16 + l15;
        const long tt = base_t + (r >> 3) * 160 + (r & 7);
        qf[ti] = *(const bf16x8*)(Q + tt * qs + h * 32 + lg * 8);
        kf[ti] = *(const bf16x8*)(KV + tt * ks + h * 32 + lg * 8);
    }
    const f32x4 zz = (f32x4){0.f, 0.f, 0.f, 0.f};
    f32x4 s[4][4];
#pragma unroll
    for (int ti = 0; ti < 4; ti++)
#pragma unroll
        for (int tj = 0; tj < 4; tj++)
            s[ti][tj] = __builtin_amdgcn_mfma_f32_16x16x32_bf16(qf[ti], kf[tj], zz, 0, 0, 0);

    {
        const long tt = base_t + (lane >> 3) * 160 + (lane & 7);
        const u16* vrow = KV + tt * ks + 256 + h * 32;
#pragma unroll
        for (int cg = 0; cg < 4; cg++) {
            bf16x8 v8 = *(const bf16x8*)(vrow + cg * 8);
#pragma unroll
            for (int j = 0; j < 8; j++) Vt[wave][(cg * 8 + j) * 72 + lane] = (u16)v8[j];
        }
    }

    const float* Bh = Bm + h * 4096;
#pragma unroll
    for (int ti = 0; ti < 4; ti++) {
#pragma unroll
        for (int r = 0; r < 4; r++) {
            const int i = ti * 16 + lg * 4 + r;
            float vv[4];
            float m = -1e30f;
#pragma unroll
            for (int tj = 0; tj < 4; tj++) {
                vv[tj] = s[ti][tj][r] + Bh[i * 64 + tj * 16 + l15];
                m = fmaxf(m, vv[tj]);
            }
#pragma unroll
            for (int off = 1; off < 16; off <<= 1) m = fmaxf(m, __shfl_xor(m, off));
            float sum = 0.f;
#pragma unroll
            for (int tj = 0; tj < 4; tj++) {
                vv[tj] = __expf(vv[tj] - m);
                sum += vv[tj];
            }
#pragma unroll
            for (int off = 1; off < 16; off <<= 1) sum += __shfl_xor(sum, off);
            const float inv = 1.f / sum;
#pragma unroll
            for (int tj = 0; tj < 4; tj++)
                Plds[wave][i * 72 + tj * 16 + l15] = f2b(vv[tj] * inv);
        }
    }

    f32x4 o[4][2];
#pragma unroll
    for (int mi = 0; mi < 4; mi++)
#pragma unroll
        for (int n = 0; n < 2; n++) o[mi][n] = zz;
#pragma unroll
    for (int c = 0; c < 2; c++) {
        bf16x8 vf[2];
#pragma unroll
        for (int n = 0; n < 2; n++)
            vf[n] = *(const bf16x8*)(&Vt[wave][(n * 16 + l15) * 72 + c * 32 + lg * 8]);
#pragma unroll
        for (int mi = 0; mi < 4; mi++) {
            bf16x8 pf = *(const bf16x8*)(&Plds[wave][(mi * 16 + l15) * 72 + c * 32 + lg * 8]);
#pragma unroll
            for (int n = 0; n < 2; n++)
                o[mi][n] = __builtin_amdgcn_mfma_f32_16x16x32_bf16(pf, vf[n], o[mi][n], 0, 0, 0);
        }
    }
#pragma unroll
    for (int mi = 0; mi < 4; mi++) {
#pragma unroll
        for (int n = 0; n < 2; n++) {
#pragma unroll
            for (int r = 0; r < 4; r++) {
                const int i = mi * 16 + lg * 4 + r;
                const long tt = base_t + (i >> 3) * 160 + (i & 7);
                AO[tt * 256 + h * 32 + n * 16 + l15] = f2b(o[mi][n][r]);
            }
        }
    }
}

// ---------------------------------------------------------------------------
extern "C" void kernel_launch(void* const* d_in, const int* in_sizes, int n_in,
                              void* d_out, int out_size, void* d_ws, size_t ws_size,
                              hipStream_t stream) {
    const float* x    = (const float*)d_in[0];
    const float* enc  = (const float*)d_in[1];
    const float* n1g  = (const float*)d_in[3];
    const float* n1b  = (const float*)d_in[4];
    const float* q1w  = (const float*)d_in[5];
    const float* q1b  = (const float*)d_in[6];
    const float* kv1w = (const float*)d_in[7];
    const float* kv1b = (const float*)d_in[8];
    const float* bias1 = (const float*)d_in[9];
    const float* p1w  = (const float*)d_in[10];
    const float* p1b  = (const float*)d_in[11];
    const float* q2w  = (const float*)d_in[12];
    const float* q2b  = (const float*)d_in[13];
    const float* kv2w = (const float*)d_in[14];
    const float* kv2b = (const float*)d_in[15];
    const float* bias2 = (const float*)d_in[16];
    const float* p2w  = (const float*)d_in[17];
    const float* p2b  = (const float*)d_in[18];
    const float* n2g  = (const float*)d_in[19];
    const float* n2b  = (const float*)d_in[20];
    const float* f1w  = (const float*)d_in[21];
    const float* f1b  = (const float*)d_in[22];
    const float* f2w  = (const float*)d_in[23];
    const float* f2bias = (const float*)d_in[24];
    float* out = (float*)d_out;

    char* ws = (char*)d_ws;
    size_t off = 0;
    auto alloc = [&](size_t bytes) {
        char* p = ws + off;
        off += (bytes + 255) & ~(size_t)255;
        return p;
    };
    u16* Wt    = (u16*)alloc(1048576 * 2);
    float* Bm  = (float*)alloc(16 * 4096 * 4);
    float* b1c = (float*)alloc(768 * 4);
    float* q2s = (float*)alloc(256 * 4);
    u16* xn    = (u16*)alloc(52428800);   // LN1 out; then y1
    u16* qb    = (u16*)alloc(52428800);   // qkv part 1 / Q2 / LN2 out
    u16* kvb   = (u16*)alloc(104857600);  // qkv part 2 / KV2 / MLP hidden
    u16* ao    = (u16*)alloc(52428800);   // attn out
    u16* encb  = (u16*)alloc(52428800);   // enc_feat bf16

    u16* qkv = qb;   // [102400][768] contiguous across qb+kvb
    u16* h1  = kvb;  // MLP hidden chunk [51200][1024]

    u16 *q1t = Wt, *p1t = Wt + 196608, *q2t = Wt + 262144,
        *kv2t = Wt + 327680, *p2t = Wt + 458752, *f1t = Wt + 524288, *f2t = Wt + 786432;

    const float qscale = 0.17677669529663687f;  // 32^-0.5

    PrepAll pa;
    pa.src[0] = q1w;  pa.dst[0] = q1t;        pa.K[0] = 256;  pa.N[0] = 256;  pa.S[0] = qscale;
    pa.src[1] = kv1w; pa.dst[1] = Wt + 65536; pa.K[1] = 256;  pa.N[1] = 512;  pa.S[1] = 1.f;
    pa.src[2] = p1w;  pa.dst[2] = p1t;        pa.K[2] = 256;  pa.N[2] = 256;  pa.S[2] = 1.f;
    pa.src[3] = q2w;  pa.dst[3] = q2t;        pa.K[3] = 256;  pa.N[3] = 256;  pa.S[3] = qscale;
    pa.src[4] = kv2w; pa.dst[4] = kv2t;       pa.K[4] = 256;  pa.N[4] = 512;  pa.S[4] = 1.f;
    pa.src[5] = p2w;  pa.dst[5] = p2t;        pa.K[5] = 256;  pa.N[5] = 256;  pa.S[5] = 1.f;
    pa.src[6] = f1w;  pa.dst[6] = f1t;        pa.K[6] = 256;  pa.N[6] = 1024; pa.S[6] = 1.f;
    pa.src[7] = f2w;  pa.dst[7] = f2t;        pa.K[7] = 1024; pa.N[7] = 256;  pa.S[7] = 1.f;
    prep_w<<<dim3(1024, 8), 256, 0, stream>>>(pa);
    prep_bias<<<dim3(64, 16), 64, 0, stream>>>(bias1, bias2, Bm);
    prep_bcat<<<dim3(3), 256, 0, stream>>>(q1b, kv1b, q2b, qscale, b1c, q2s);
    cast_bf<<<dim3(12800), 256, 0, stream>>>(enc, encb);
    ln256<<<dim3(25600), 256, 0, stream>>>(x, n1g, n1b, xn);

    // stage 1: fused QKV gemm (Q pre-scaled), attn, proj
    gemmP<0, 8><<<dim3(4800), 256, 0, stream>>>(xn, q1t, b1c, nullptr, qkv, nullptr, 768, 6);
    attn64<<<dim3(3200), 256, 0, stream>>>(qkv, 768, qkv + 256, 768, Bm, ao);
    gemmP<0, 8><<<dim3(1600), 256, 0, stream>>>(ao, p1t, p1b, nullptr, xn, nullptr, 256, 2);

    // stage 2: cross-attention to encoder features
    gemmP<0, 8><<<dim3(1600), 256, 0, stream>>>(xn, q2t, q2s, nullptr, qb, nullptr, 256, 2);
    gemmP<0, 8><<<dim3(3200), 256, 0, stream>>>(encb, kv2t, kv2b, nullptr, kvb, nullptr, 512, 4);
    attn64<<<dim3(3200), 256, 0, stream>>>(qb, 256, kvb, 512, Bm + 8 * 4096, ao);

    // proj2 + shortcut residual -> fp32 in d_out
    gemmP<3, 8><<<dim3(1600), 256, 0, stream>>>(ao, p2t, p2b, x, (u16*)nullptr, out, 256, 2);

    // MLP: LN2 -> fc1+gelu -> fc2+residual (in-place), 2 row-chunks
    ln256<<<dim3(25600), 256, 0, stream>>>(out, n2g, n2b, qb);
    for (int c = 0; c < 2; c++) {
        const u16* xh = qb + (size_t)c * 51200 * 256;
        float* oc = out + (size_t)c * 51200 * 256;
        gemmP<2, 8><<<dim3(3200), 256, 0, stream>>>(xh, f1t, f1b, nullptr, h1, nullptr, 1024, 8);
        gemmP<3, 32><<<dim3(800), 256, 0, stream>>>(h1, f2t, f2bias, oc, (u16*)nullptr, oc, 256, 2);
    }
}